// Round 13
// baseline (244.366 us; speedup 1.0000x reference)
//
#include <hip/hip_runtime.h>

#define C_CLUST 8
#define N_PAT   16384
#define D_FEAT  1024
#define DQ_DIM  128
#define K_TOP   128

// 1/sqrt(128) and 1/sqrt(1024)
#define INV_S128 0.08838834764831844055
#define INV_S1024 0.03125

// ---------- helpers ----------
__device__ inline unsigned f2key(float f) {
    unsigned u = __float_as_uint(f);
    return (u & 0x80000000u) ? ~u : (u | 0x80000000u);
}
__device__ inline float key2f(unsigned k) {
    unsigned u = (k & 0x80000000u) ? (k ^ 0x80000000u) : ~k;
    return __uint_as_float(u);
}
__device__ inline unsigned long long shfl_xor_u64(unsigned long long v, int m) {
    unsigned lo = (unsigned)v, hi = (unsigned)(v >> 32);
    lo = __shfl_xor(lo, m, 64);
    hi = __shfl_xor(hi, m, 64);
    return ((unsigned long long)hi << 32) | lo;
}

// ============ kernel 1: prep — qk (redundant per block) + r slice + b0 (R11/R12-validated) ============
// grid 64 blocks: b = c*8 + g (g = 128-d slice) ; 1024 threads
__global__ __launch_bounds__(1024) void prep_kernel(
    const float* __restrict__ key_feats,  // [C,1,D]
    const float* __restrict__ Wq,         // [D,DQ]
    const float* __restrict__ bq,         // [DQ]
    double* __restrict__ r,               // [C][D]
    double* __restrict__ b0)              // [C]
{
    __shared__ float keyrow[D_FEAT];
    __shared__ double part[1024];
    __shared__ double qk_lds[DQ_DIM];
    const int b = blockIdx.x;
    const int c = b >> 3, g = b & 7;
    const int tid = threadIdx.x;
    const int lane = tid & 63, wv = tid >> 6;   // 16 waves

    keyrow[tid] = key_feats[c * D_FEAT + tid];
    __syncthreads();

    {   // qk[j] = key . Wq[:,j] + bq[j]  (8-way split-d partials)
        const int j = tid & 127, s = tid >> 7;
        double acc = 0.0;
        for (int d = s; d < D_FEAT; d += 8)
            acc += (double)keyrow[d] * (double)Wq[d * DQ_DIM + j];
        part[s * DQ_DIM + j] = acc;
    }
    __syncthreads();
    if (tid < DQ_DIM) {
        double v = part[tid];
#pragma unroll
        for (int s2 = 1; s2 < 8; ++s2) v += part[s2 * DQ_DIM + tid];
        qk_lds[tid] = v + (double)bq[tid];
    }
    __syncthreads();

    if (g == 0 && wv == 0) {   // b0 = bq . qk
        double p = (double)bq[lane] * qk_lds[lane] + (double)bq[64 + lane] * qk_lds[64 + lane];
#pragma unroll
        for (int o = 32; o > 0; o >>= 1) p += __shfl_xor(p, o, 64);
        if (lane == 0) b0[c] = p;
    }

    {   // r slice: d in [g*128, g*128+128); wave wv handles 8 d's
        const double q0 = qk_lds[lane], q1 = qk_lds[64 + lane];
        const int d0 = g * 128 + wv * 8;
#pragma unroll
        for (int i = 0; i < 8; ++i) {
            const int d = d0 + i;
            double a = (double)Wq[d * DQ_DIM + lane] * q0
                     + (double)Wq[d * DQ_DIM + 64 + lane] * q1;
#pragma unroll
            for (int o = 32; o > 0; o >>= 1) a += __shfl_xor(a, o, 64);
            if (lane == 0) r[c * D_FEAT + d] = a;
        }
    }
}

// ============ kernel 2: scores — r in VGPRs, 16 rows per wave (R7-validated) ============
// grid 2048 blocks x 256 thr = 8 waves/SIMD
__global__ __launch_bounds__(256) void score_kernel(
    const float* __restrict__ feats,      // [C,N,D]
    const double* __restrict__ r,         // [C][D]
    const double* __restrict__ b0,        // [C]
    float* __restrict__ scores)           // [C][N]
{
    const int w    = blockIdx.x * 4 + (threadIdx.x >> 6); // wave id, 0..8191
    const int lane = threadIdx.x & 63;
    const int c  = w >> 10;
    const int n0 = (w & 1023) * 16;

    const double* rp = r + c * D_FEAT;
    double rr[16];
#pragma unroll
    for (int it = 0; it < 4; ++it)
#pragma unroll
        for (int j = 0; j < 4; ++j)
            rr[it * 4 + j] = rp[it * 256 + lane * 4 + j];
    const double bb = b0[c];

    const float4* fbase = (const float4*)(feats + (size_t)(c * N_PAT + n0) * D_FEAT);
    float* sout = scores + c * N_PAT + n0;

    for (int rI = 0; rI < 16; rI += 2) {
        const float4* fp0 = fbase + (size_t)(rI + 0) * 256;
        const float4* fp1 = fbase + (size_t)(rI + 1) * 256;
        double acc0 = 0.0, acc1 = 0.0;
#pragma unroll
        for (int it = 0; it < 4; ++it) {
            float4 f0 = fp0[it * 64 + lane];
            float4 f1 = fp1[it * 64 + lane];
            acc0 += (double)f0.x * rr[it * 4 + 0];
            acc0 += (double)f0.y * rr[it * 4 + 1];
            acc0 += (double)f0.z * rr[it * 4 + 2];
            acc0 += (double)f0.w * rr[it * 4 + 3];
            acc1 += (double)f1.x * rr[it * 4 + 0];
            acc1 += (double)f1.y * rr[it * 4 + 1];
            acc1 += (double)f1.z * rr[it * 4 + 2];
            acc1 += (double)f1.w * rr[it * 4 + 3];
        }
#pragma unroll
        for (int o = 32; o > 0; o >>= 1) {
            acc0 += __shfl_xor(acc0, o, 64);
            acc1 += __shfl_xor(acc1, o, 64);
        }
        if (lane == 0) {
            sout[rI + 0] = (float)(acc0 + bb);
            sout[rI + 1] = (float)(acc1 + bb);
        }
    }
}

// ============ kernel 3: topk — ballot radix (2 barriers/pass) + wave-0 register bitonic ============
// grid 8 blocks x 1024 threads
__global__ __launch_bounds__(1024) void topk_kernel(
    const float* __restrict__ scores,     // [C][N]
    int* __restrict__ top_idx,            // [C][K]
    double* __restrict__ Aw)              // [C][K]
{
    const int c = blockIdx.x;
    const int tid = threadIdx.x;
    const int lane = tid & 63, wid = tid >> 6;

    __shared__ double   red_d[16];
    __shared__ unsigned red_u[16];
    __shared__ unsigned bcast_u;
    __shared__ double   bcast_d;
    __shared__ unsigned hist16[16][16];    // [wave][bucket]
    __shared__ unsigned bcast_b, bcast_need;
    __shared__ int cntG, cntE;
    __shared__ int idxG[K_TOP];
    __shared__ int idxE[256];
    __shared__ int list[K_TOP];

    // 16 scores per thread, register-resident
    float sv[16];
    unsigned uk[16];
#pragma unroll
    for (int k = 0; k < 16; ++k) {
        sv[k] = scores[c * N_PAT + k * 1024 + tid];
        uk[k] = f2key(sv[k]);
    }

    // block max (R7-validated, 2 barriers)
    unsigned mk = 0;
#pragma unroll
    for (int k = 0; k < 16; ++k) mk = max(mk, uk[k]);
#pragma unroll
    for (int o = 32; o > 0; o >>= 1) mk = max(mk, __shfl_xor(mk, o, 64));
    if (lane == 0) red_u[wid] = mk;
    __syncthreads();
    if (tid == 0) {
        unsigned m = 0;
        for (int i = 0; i < 16; ++i) m = max(m, red_u[i]);
        bcast_u = m;
    }
    __syncthreads();
    const double m_t = (double)key2f(bcast_u) * INV_S128;

    // Z (R7-validated, 2 barriers)
    double zs = 0.0;
#pragma unroll
    for (int k = 0; k < 16; ++k)
        zs += (double)__expf((float)((double)sv[k] * INV_S128 - m_t));
#pragma unroll
    for (int o = 32; o > 0; o >>= 1) zs += __shfl_xor(zs, o, 64);
    if (lane == 0) red_d[wid] = zs;
    __syncthreads();
    if (tid == 0) {
        double z = 0.0;
        for (int i = 0; i < 16; ++i) z += red_d[i];
        bcast_d = z;
    }
    __syncthreads();
    const double Z = bcast_d;

    // ---- ballot radix select (4-bit, 8 passes, 2 barriers/pass) ----
    unsigned pref = 0;
    int need = K_TOP;
    for (int p = 7; p >= 0; --p) {
        const unsigned hmask = (p == 7) ? 0u : (0xFFFFFFFFu << (4 * (p + 1)));
        const unsigned bkt = (unsigned)lane & 15u;
        unsigned cnt = 0;
#pragma unroll
        for (int k = 0; k < 16; ++k) {
            bool act = (uk[k] & hmask) == pref;
            unsigned nib = (uk[k] >> (4 * p)) & 15u;
            unsigned long long mact = __ballot(act);
            unsigned long long m0 = __ballot((nib & 1u) != 0u);
            unsigned long long m1 = __ballot((nib & 2u) != 0u);
            unsigned long long m2 = __ballot((nib & 4u) != 0u);
            unsigned long long m3 = __ballot((nib & 8u) != 0u);
            unsigned long long sel = ((bkt & 1u) ? m0 : ~m0)
                                   & ((bkt & 2u) ? m1 : ~m1)
                                   & ((bkt & 4u) ? m2 : ~m2)
                                   & ((bkt & 8u) ? m3 : ~m3) & mact;
            cnt += (unsigned)__popcll(sel);
        }
        if (lane < 16) hist16[wid][lane] = cnt;
        __syncthreads();
        if (wid == 0) {           // wave 0: reduce across waves + in-wave suffix scan
            unsigned t = 0;
            if (lane < 16) {
#pragma unroll
                for (int w2 = 0; w2 < 16; ++w2) t += hist16[w2][lane];
            }
            unsigned s = t;
#pragma unroll
            for (int off = 1; off < 16; off <<= 1) {
                unsigned o = __shfl_down(s, off, 64);
                if (lane + off < 16) s += o;
            }
            if (lane < 16) {
                unsigned hi = s - t;      // count of nibble > lane
                if (s >= (unsigned)need && hi < (unsigned)need) {
                    bcast_b = (unsigned)lane;
                    bcast_need = (unsigned)need - hi;
                }
            }
        }
        __syncthreads();
        pref |= bcast_b << (4 * p);
        need = (int)bcast_need;
    }
    const unsigned lo = pref;   // threshold key

    // ---- collect (R7-validated) ----
    if (tid == 0) { cntG = 0; cntE = 0; }
    __syncthreads();
#pragma unroll
    for (int k = 0; k < 16; ++k) {
        int n = k * 1024 + tid;
        if (uk[k] > lo) {
            int p = atomicAdd(&cntG, 1);
            idxG[p] = n;
        } else if (uk[k] == lo) {
            int p = atomicAdd(&cntE, 1);
            if (p < 256) idxE[p] = n;
        }
    }
    __syncthreads();
    const int nG = cntG;
    const int nE = min(cntE, 256);
    if (tid == 0) {
        for (int i = 1; i < nE; ++i) {
            int v = idxE[i]; int j = i - 1;
            while (j >= 0 && idxE[j] > v) { idxE[j + 1] = idxE[j]; --j; }
            idxE[j + 1] = v;
        }
    }
    __syncthreads();
    if (tid < K_TOP) list[tid] = (tid < nG) ? idxG[tid] : idxE[tid - nG];
    __syncthreads();

    // ---- wave 0: register bitonic sort of 128 composite keys (2/lane, ZERO barriers) ----
    if (wid == 0) {
        const int idxA = list[lane], idxB = list[lane + 64];
        unsigned long long v0 = ((unsigned long long)f2key(scores[c * N_PAT + idxA]) << 32)
                              | (unsigned)(~(unsigned)idxA);
        unsigned long long v1 = ((unsigned long long)f2key(scores[c * N_PAT + idxB]) << 32)
                              | (unsigned)(~(unsigned)idxB);
        // k = 2..64 (cross-lane; slot parity identical for k<64, split for k=64)
        for (int k = 2; k <= 64; k <<= 1) {
            for (int j = k >> 1; j > 0; j >>= 1) {
                const bool d0 = (k == 64) ? true  : ((lane & k) == 0);
                const bool d1 = (k == 64) ? false : d0;
                const bool lower = ((lane & j) == 0);
                unsigned long long o0 = shfl_xor_u64(v0, j);
                unsigned long long o1 = shfl_xor_u64(v1, j);
                v0 = (lower == d0) ? (v0 > o0 ? v0 : o0) : (v0 < o0 ? v0 : o0);
                v1 = (lower == d1) ? (v1 > o1 ? v1 : o1) : (v1 < o1 ? v1 : o1);
            }
        }
        // k = 128: j=64 is the in-lane swap (desc), then j=32..1 desc both slots
        {
            unsigned long long hi = v0 > v1 ? v0 : v1;
            unsigned long long lo2 = v0 > v1 ? v1 : v0;
            v0 = hi; v1 = lo2;
        }
        for (int j = 32; j > 0; j >>= 1) {
            const bool lower = ((lane & j) == 0);
            unsigned long long o0 = shfl_xor_u64(v0, j);
            unsigned long long o1 = shfl_xor_u64(v1, j);
            v0 = lower ? (v0 > o0 ? v0 : o0) : (v0 < o0 ? v0 : o0);
            v1 = lower ? (v1 > o1 ? v1 : o1) : (v1 < o1 ? v1 : o1);
        }
        // outputs: top_idx, pd, Aw — all in-wave
        const int oidx0 = (int)(~(unsigned)(v0 & 0xFFFFFFFFull));
        const int oidx1 = (int)(~(unsigned)(v1 & 0xFFFFFFFFull));
        top_idx[c * K_TOP + lane]      = oidx0;
        top_idx[c * K_TOP + 64 + lane] = oidx1;
        const double p0 = exp((double)key2f((unsigned)(v0 >> 32)) * INV_S128 - m_t) / Z;
        const double p1 = exp((double)key2f((unsigned)(v1 >> 32)) * INV_S128 - m_t) / Z;
        const double pmax = __shfl(p0, 0, 64);   // sorted desc -> lane 0 slot 0 is max
        const double e0 = exp((p0 - pmax) * INV_S1024);
        const double e1 = exp((p1 - pmax) * INV_S1024);
        double tot = e0 + e1;
#pragma unroll
        for (int o = 32; o > 0; o >>= 1) tot += __shfl_xor(tot, o, 64);
        Aw[c * K_TOP + lane]      = e0 / tot;
        Aw[c * K_TOP + 64 + lane] = e1 / tot;
    }
}

// ============ kernel 4: fused gather (rows -> out) + partial weighted sum (R7-validated) ============
// grid: C * 4(d-quarter) * 4(i-chunk) = 128 blocks
__global__ __launch_bounds__(256) void gather_wsum_kernel(
    const float* __restrict__ feats,
    const int* __restrict__ top_idx,
    const double* __restrict__ Aw,
    float* __restrict__ out,              // [C*K, D] at offset 0
    double* __restrict__ w_part)          // [C][4][D]
{
    __shared__ double sa[32];
    __shared__ int sidx[32];
    const int b = blockIdx.x;
    const int c = b >> 4, quarter = (b >> 2) & 3, ich = b & 3;
    const int tid = threadIdx.x;           // 256
    if (tid < 32) {
        sa[tid] = Aw[c * K_TOP + ich * 32 + tid];
        sidx[tid] = top_idx[c * K_TOP + ich * 32 + tid];
    }
    __syncthreads();
    const int d = quarter * 256 + tid;
    const float* fc = feats + (size_t)c * N_PAT * D_FEAT + d;
    float* oc = out + ((size_t)c * K_TOP + ich * 32) * D_FEAT + d;
    double a0 = 0.0, a1 = 0.0, a2 = 0.0, a3 = 0.0;
#pragma unroll 2
    for (int i = 0; i < 32; i += 4) {
        float v0 = fc[(size_t)sidx[i + 0] * D_FEAT];
        float v1 = fc[(size_t)sidx[i + 1] * D_FEAT];
        float v2 = fc[(size_t)sidx[i + 2] * D_FEAT];
        float v3 = fc[(size_t)sidx[i + 3] * D_FEAT];
        oc[(size_t)(i + 0) * D_FEAT] = v0;
        oc[(size_t)(i + 1) * D_FEAT] = v1;
        oc[(size_t)(i + 2) * D_FEAT] = v2;
        oc[(size_t)(i + 3) * D_FEAT] = v3;
        a0 += sa[i + 0] * (double)v0;
        a1 += sa[i + 1] * (double)v1;
        a2 += sa[i + 2] * (double)v2;
        a3 += sa[i + 3] * (double)v3;
    }
    w_part[((size_t)(c * 4 + ich)) * D_FEAT + d] = (a0 + a1) + (a2 + a3);
}

// ============ kernel 5: fusion = (sum w_part) @ Wv + bv (R7-validated, in-block split-K) ============
// grid: C * 8(dp-chunks of 128) = 64 blocks x 256 thr
__global__ __launch_bounds__(256) void fusion_kernel(
    const double* __restrict__ w_part,    // [C][4][D]
    const float* __restrict__ Wv,         // [D,D]
    const float* __restrict__ bv,         // [D]
    float* __restrict__ out)              // fusion at offset C*K*D
{
    __shared__ double w_lds[D_FEAT];
    __shared__ double partl[2][128];
    const int b = blockIdx.x;
    const int c = b >> 3, dpg = b & 7;
    const int tid = threadIdx.x;           // 256

    for (int d = tid; d < D_FEAT; d += 256) {
        double s = 0.0;
#pragma unroll
        for (int ich = 0; ich < 4; ++ich)
            s += w_part[((size_t)(c * 4 + ich)) * D_FEAT + d];
        w_lds[d] = s;
    }
    __syncthreads();

    const int dpl = tid & 127, half = tid >> 7;
    const int dp = dpg * 128 + dpl;
    const double* wc = w_lds + half * 512;
    const float* wvp = Wv + (size_t)(half * 512) * D_FEAT + dp;
    double a0 = 0.0, a1 = 0.0, a2 = 0.0, a3 = 0.0;
#pragma unroll 2
    for (int d = 0; d < 512; d += 4) {
        a0 += wc[d + 0] * (double)wvp[(size_t)(d + 0) * D_FEAT];
        a1 += wc[d + 1] * (double)wvp[(size_t)(d + 1) * D_FEAT];
        a2 += wc[d + 2] * (double)wvp[(size_t)(d + 2) * D_FEAT];
        a3 += wc[d + 3] * (double)wvp[(size_t)(d + 3) * D_FEAT];
    }
    partl[half][dpl] = (a0 + a1) + (a2 + a3);
    __syncthreads();
    if (half == 0) {
        double acc = (double)bv[dp] + partl[0][dpl] + partl[1][dpl];
        out[(size_t)(C_CLUST * K_TOP * D_FEAT) + c * D_FEAT + dp] = (float)acc;
    }
}

extern "C" void kernel_launch(void* const* d_in, const int* in_sizes, int n_in,
                              void* d_out, int out_size, void* d_ws, size_t ws_size,
                              hipStream_t stream) {
    const float* feats     = (const float*)d_in[0];  // [8,16384,1024]
    const float* key_feats = (const float*)d_in[1];  // [8,1,1024]
    const float* Wq        = (const float*)d_in[2];  // [1024,128]
    const float* bq        = (const float*)d_in[3];  // [128]
    const float* Wv        = (const float*)d_in[4];  // [1024,1024]
    const float* bv        = (const float*)d_in[5];  // [1024]
    float* out = (float*)d_out;

    char* ws = (char*)d_ws;
    float*  scores  = (float*)(ws + 0);        // 8*16384*4   = 524288
    double* r       = (double*)(ws + 524288);  // 8*1024*8    = 65536
    double* b0      = (double*)(ws + 589824);  // 8*8         = 64
    int*    top_idx = (int*)(ws + 589888);     // 8*128*4     = 4096
    double* Aw      = (double*)(ws + 593984);  // 8*128*8     = 8192
    double* w_part  = (double*)(ws + 602176);  // 8*4*1024*8  = 262144  (end 864320)

    hipLaunchKernelGGL(prep_kernel,        dim3(64),   dim3(1024), 0, stream,
                       key_feats, Wq, bq, r, b0);
    hipLaunchKernelGGL(score_kernel,       dim3(2048), dim3(256),  0, stream,
                       feats, r, b0, scores);
    hipLaunchKernelGGL(topk_kernel,        dim3(C_CLUST), dim3(1024), 0, stream,
                       scores, top_idx, Aw);
    hipLaunchKernelGGL(gather_wsum_kernel, dim3(128),  dim3(256),  0, stream,
                       feats, top_idx, Aw, out, w_part);
    hipLaunchKernelGGL(fusion_kernel,      dim3(64),   dim3(256),  0, stream,
                       w_part, Wv, bv, out);
}

// Round 14
// 193.398 us; speedup vs baseline: 1.2635x; 1.2635x over previous
//
#include <hip/hip_runtime.h>

#define C_CLUST 8
#define N_PAT   16384
#define D_FEAT  1024
#define DQ_DIM  128
#define K_TOP   128
#define NCHUNK  32          // 512-row chunks per cluster
#define CHROWS  512

// 1/sqrt(128) and 1/sqrt(1024)
#define INV_S128 0.08838834764831844055
#define INV_S1024 0.03125

// ---------- helpers ----------
__device__ inline unsigned f2key(float f) {
    unsigned u = __float_as_uint(f);
    return (u & 0x80000000u) ? ~u : (u | 0x80000000u);
}
__device__ inline float key2f(unsigned k) {
    unsigned u = (k & 0x80000000u) ? (k ^ 0x80000000u) : ~k;
    return __uint_as_float(u);
}

// ============ kernel 1a: qk partials — block (c, sg) covers 64 d's, thread = j (R7-validated) ============
__global__ __launch_bounds__(128) void qk_kernel(
    const float* __restrict__ key_feats,  // [C,1,D]
    const float* __restrict__ Wq,         // [D,DQ]
    double* __restrict__ qk_part)         // [C][16][DQ]
{
    const int b = blockIdx.x;              // c*16 + sg
    const int c = b >> 4, sg = b & 15;
    const int j = threadIdx.x;             // 0..127
    const int d0 = sg * 64;
    double acc = 0.0;
#pragma unroll 4
    for (int d = d0; d < d0 + 64; ++d)
        acc += (double)key_feats[c * D_FEAT + d] * (double)Wq[d * DQ_DIM + j];
    qk_part[(size_t)(c * 16 + sg) * DQ_DIM + j] = acc;
}

// ============ kernel 1b: r[c][d] = Wq[d,:] . (qk_sum + bq); d==0 wave emits b0 (R7-validated) ============
__global__ __launch_bounds__(256) void r_kernel(
    const float* __restrict__ Wq,         // [D,DQ]
    const float* __restrict__ bq,         // [DQ]
    const double* __restrict__ qk_part,   // [C][16][DQ]
    double* __restrict__ r,               // [C][D]
    double* __restrict__ b0)              // [C]
{
    const int w = blockIdx.x * 4 + (threadIdx.x >> 6);   // 0..8191
    const int lane = threadIdx.x & 63;
    const int c = w >> 10, d = w & (D_FEAT - 1);

    double q0 = (double)bq[lane];
    double q1 = (double)bq[64 + lane];
#pragma unroll
    for (int sg = 0; sg < 16; ++sg) {
        q0 += qk_part[(size_t)(c * 16 + sg) * DQ_DIM + lane];
        q1 += qk_part[(size_t)(c * 16 + sg) * DQ_DIM + 64 + lane];
    }

    double a = (double)Wq[d * DQ_DIM + lane] * q0
             + (double)Wq[d * DQ_DIM + 64 + lane] * q1;
#pragma unroll
    for (int o = 32; o > 0; o >>= 1) a += __shfl_xor(a, o, 64);
    if (lane == 0) r[c * D_FEAT + d] = a;

    if (d == 0) {   // this wave also computes b0[c] = bq . qk
        double p = (double)bq[lane] * q0 + (double)bq[64 + lane] * q1;
#pragma unroll
        for (int o = 32; o > 0; o >>= 1) p += __shfl_xor(p, o, 64);
        if (lane == 0) b0[c] = p;
    }
}

// ============ kernel 2: scores — r in VGPRs, 16 rows per wave (R7-validated) ============
// grid 2048 blocks x 256 thr = 8 waves/SIMD
__global__ __launch_bounds__(256) void score_kernel(
    const float* __restrict__ feats,      // [C,N,D]
    const double* __restrict__ r,         // [C][D]
    const double* __restrict__ b0,        // [C]
    float* __restrict__ scores)           // [C][N]
{
    const int w    = blockIdx.x * 4 + (threadIdx.x >> 6); // wave id, 0..8191
    const int lane = threadIdx.x & 63;
    const int c  = w >> 10;
    const int n0 = (w & 1023) * 16;

    const double* rp = r + c * D_FEAT;
    double rr[16];
#pragma unroll
    for (int it = 0; it < 4; ++it)
#pragma unroll
        for (int j = 0; j < 4; ++j)
            rr[it * 4 + j] = rp[it * 256 + lane * 4 + j];
    const double bb = b0[c];

    const float4* fbase = (const float4*)(feats + (size_t)(c * N_PAT + n0) * D_FEAT);
    float* sout = scores + c * N_PAT + n0;

    for (int rI = 0; rI < 16; rI += 2) {
        const float4* fp0 = fbase + (size_t)(rI + 0) * 256;
        const float4* fp1 = fbase + (size_t)(rI + 1) * 256;
        double acc0 = 0.0, acc1 = 0.0;
#pragma unroll
        for (int it = 0; it < 4; ++it) {
            float4 f0 = fp0[it * 64 + lane];
            float4 f1 = fp1[it * 64 + lane];
            acc0 += (double)f0.x * rr[it * 4 + 0];
            acc0 += (double)f0.y * rr[it * 4 + 1];
            acc0 += (double)f0.z * rr[it * 4 + 2];
            acc0 += (double)f0.w * rr[it * 4 + 3];
            acc1 += (double)f1.x * rr[it * 4 + 0];
            acc1 += (double)f1.y * rr[it * 4 + 1];
            acc1 += (double)f1.z * rr[it * 4 + 2];
            acc1 += (double)f1.w * rr[it * 4 + 3];
        }
#pragma unroll
        for (int o = 32; o > 0; o >>= 1) {
            acc0 += __shfl_xor(acc0, o, 64);
            acc1 += __shfl_xor(acc1, o, 64);
        }
        if (lane == 0) {
            sout[rI + 0] = (float)(acc0 + bb);
            sout[rI + 1] = (float)(acc1 + bb);
        }
    }
}

// ============ kernel 3: 512-row chunk bitonic top-128 + softmax partials (R12-validated) ============
// grid 256 blocks: b = c*32 + chunk ; 256 threads (2 elems/thread)
__global__ __launch_bounds__(256) void chunksort_kernel(
    const float* __restrict__ scores,        // [C][N]
    unsigned long long* __restrict__ cand,   // [C][32][128]
    unsigned* __restrict__ mxkey,            // [C][32]
    double* __restrict__ Ssum)               // [C][32]
{
    const int b = blockIdx.x;
    const int c = b >> 5, chunk = b & 31;
    const int tid = threadIdx.x;
    const int lane = tid & 63, wv = tid >> 6;

    __shared__ unsigned long long su[CHROWS];
    __shared__ unsigned ured[4];
    __shared__ double dred[4];
    __shared__ unsigned bmax_s;

    const int base = c * N_PAT + chunk * CHROWS;
    const float s0 = scores[base + tid];
    const float s1 = scores[base + 256 + tid];
    const unsigned k0 = f2key(s0), k1 = f2key(s1);
    su[tid]       = ((unsigned long long)k0 << 32) | (unsigned)(~(unsigned)(chunk * CHROWS + tid));
    su[tid + 256] = ((unsigned long long)k1 << 32) | (unsigned)(~(unsigned)(chunk * CHROWS + 256 + tid));

    unsigned mk = max(k0, k1);
#pragma unroll
    for (int o = 32; o > 0; o >>= 1) mk = max(mk, __shfl_xor(mk, o, 64));
    if (lane == 0) ured[wv] = mk;
    __syncthreads();
    if (tid == 0) bmax_s = max(max(ured[0], ured[1]), max(ured[2], ured[3]));
    __syncthreads();
    const unsigned kmax = bmax_s;
    const double mx_t = (double)key2f(kmax) * INV_S128;
    double es = (double)__expf((float)((double)s0 * INV_S128 - mx_t))
              + (double)__expf((float)((double)s1 * INV_S128 - mx_t));
#pragma unroll
    for (int o = 32; o > 0; o >>= 1) es += __shfl_xor(es, o, 64);
    if (lane == 0) dred[wv] = es;
    __syncthreads();
    if (tid == 0) {
        Ssum[c * NCHUNK + chunk] = dred[0] + dred[1] + dred[2] + dred[3];
        mxkey[c * NCHUNK + chunk] = kmax;
    }

    // bitonic sort 512 descending (composite: value desc, index asc)
    for (int k = 2; k <= CHROWS; k <<= 1) {
        for (int j = k >> 1; j > 0; j >>= 1) {
            __syncthreads();
#pragma unroll
            for (int ii = 0; ii < 2; ++ii) {
                const int i = ii * 256 + tid, l = i ^ j;
                if (l > i) {
                    unsigned long long a = su[i], b2 = su[l];
                    const bool desc = ((i & k) == 0);
                    if (desc ? (a < b2) : (a > b2)) { su[i] = b2; su[l] = a; }
                }
            }
        }
    }
    __syncthreads();
    if (tid < K_TOP) cand[(size_t)(c * NCHUNK + chunk) * K_TOP + tid] = su[tid];
}

// ============ kernel 4: replicated merge + Aw + gather slice + w_part (R12-validated) ============
// grid 128 blocks: b = c*16 + quarter*4 + ich ; 256 threads
__global__ __launch_bounds__(256) void gather_merge_kernel(
    const float* __restrict__ feats,
    const unsigned long long* __restrict__ cand,  // [C][32*128]
    const unsigned* __restrict__ mxkey,           // [C][32]
    const double* __restrict__ Ssum,              // [C][32]
    float* __restrict__ out,                      // rows at offset 0
    double* __restrict__ w_part)                  // [C][4][D]
{
    const int b = blockIdx.x;
    const int c = b >> 4, quarter = (b >> 2) & 3, ich = b & 3;
    const int tid = threadIdx.x;
    const int lane = tid & 63, wv = tid >> 6;

    __shared__ unsigned long long su2[4096];      // 32 KB
    __shared__ double pd[K_TOP];
    __shared__ double sa[K_TOP];
    __shared__ int sidx[K_TOP];
    __shared__ double dred2[2];
    __shared__ double sZ;

#pragma unroll
    for (int k = 0; k < 16; ++k)
        su2[k * 256 + tid] = cand[(size_t)c * 4096 + k * 256 + tid];
    __syncthreads();

    // ---- bitonic top-k tree merge: 32 desc-sorted 128-lists -> top-128 ----
    for (int nl = 32; nl > 1; nl >>= 1) {
        const int half = nl >> 1;
        const int total = half * K_TOP;           // <= 2048
        unsigned long long tmp[8];
        int cnt = 0;
        for (int i = tid; i < total; i += 256) {  // C[i] = max(A[i], B[127-i])
            const int g = i >> 7, li = i & 127;
            unsigned long long a  = su2[(2 * g) * K_TOP + li];
            unsigned long long b2 = su2[(2 * g + 1) * K_TOP + (K_TOP - 1 - li)];
            tmp[cnt++] = a > b2 ? a : b2;
        }
        __syncthreads();
        cnt = 0;
        for (int i = tid; i < total; i += 256) su2[i] = tmp[cnt++];
        __syncthreads();
        for (int j = 64; j > 0; j >>= 1) {        // clean bitonic 128-lists, desc
            for (int i = tid; i < total; i += 256) {
                const int li = i & 127, l = li ^ j;
                if (l > li) {
                    const int base = i - li;
                    unsigned long long a = su2[base + li], b2 = su2[base + l];
                    if (a < b2) { su2[base + li] = b2; su2[base + l] = a; }
                }
            }
            __syncthreads();
        }
    }

    const double m_t = (double)key2f((unsigned)(su2[0] >> 32)) * INV_S128;
    if (wv == 0) {   // Z = sum over 32 chunks of Ssum * exp(mx_chunk - m_global)
        double z = (lane < NCHUNK)
            ? Ssum[c * NCHUNK + lane] * exp((double)key2f(mxkey[c * NCHUNK + lane]) * INV_S128 - m_t)
            : 0.0;
#pragma unroll
        for (int o = 32; o > 0; o >>= 1) z += __shfl_xor(z, o, 64);
        if (lane == 0) sZ = z;
    }
    __syncthreads();
    const double Z = sZ;
    if (tid < K_TOP) {
        unsigned long long pr = su2[tid];
        sidx[tid] = (int)(~(unsigned)(pr & 0xFFFFFFFFull));
        pd[tid] = exp((double)key2f((unsigned)(pr >> 32)) * INV_S128 - m_t) / Z;
    }
    __syncthreads();
    if (tid < K_TOP) {
        double e = exp((pd[tid] - pd[0]) * INV_S1024);   // pd[0] is max (sorted)
        double se = e;
#pragma unroll
        for (int o = 32; o > 0; o >>= 1) se += __shfl_xor(se, o, 64);
        if (lane == 0) dred2[wv] = se;
    }
    __syncthreads();
    if (tid < K_TOP) {
        double tot = dred2[0] + dred2[1];
        sa[tid] = exp((pd[tid] - pd[0]) * INV_S1024) / tot;
    }
    __syncthreads();

    // ---- gather slice + partial weighted sum ----
    const int d = quarter * 256 + tid;
    const float* fc = feats + (size_t)c * N_PAT * D_FEAT + d;
    float* oc = out + ((size_t)c * K_TOP + ich * 32) * D_FEAT + d;
    double a0 = 0.0, a1 = 0.0, a2 = 0.0, a3 = 0.0;
#pragma unroll 2
    for (int i = 0; i < 32; i += 4) {
        const int i0 = ich * 32 + i;
        float v0 = fc[(size_t)sidx[i0 + 0] * D_FEAT];
        float v1 = fc[(size_t)sidx[i0 + 1] * D_FEAT];
        float v2 = fc[(size_t)sidx[i0 + 2] * D_FEAT];
        float v3 = fc[(size_t)sidx[i0 + 3] * D_FEAT];
        oc[(size_t)(i + 0) * D_FEAT] = v0;
        oc[(size_t)(i + 1) * D_FEAT] = v1;
        oc[(size_t)(i + 2) * D_FEAT] = v2;
        oc[(size_t)(i + 3) * D_FEAT] = v3;
        a0 += sa[i0 + 0] * (double)v0;
        a1 += sa[i0 + 1] * (double)v1;
        a2 += sa[i0 + 2] * (double)v2;
        a3 += sa[i0 + 3] * (double)v3;
    }
    w_part[((size_t)(c * 4 + ich)) * D_FEAT + d] = (a0 + a1) + (a2 + a3);
}

// ============ kernel 5: fusion = (sum w_part) @ Wv + bv (R12-validated split-K) ============
// grid: C * 8(dp-chunks of 128) = 64 blocks x 256 thr
__global__ __launch_bounds__(256) void fusion_kernel(
    const double* __restrict__ w_part,    // [C][4][D]
    const float* __restrict__ Wv,         // [D,D]
    const float* __restrict__ bv,         // [D]
    float* __restrict__ out)              // fusion at offset C*K*D
{
    __shared__ double w_lds[D_FEAT];
    __shared__ double partl[2][128];
    const int b = blockIdx.x;
    const int c = b >> 3, dpg = b & 7;
    const int tid = threadIdx.x;           // 256

    for (int d = tid; d < D_FEAT; d += 256) {
        double s = 0.0;
#pragma unroll
        for (int ich = 0; ich < 4; ++ich)
            s += w_part[((size_t)(c * 4 + ich)) * D_FEAT + d];
        w_lds[d] = s;
    }
    __syncthreads();

    const int dpl = tid & 127, half = tid >> 7;
    const int dp = dpg * 128 + dpl;
    const double* wc = w_lds + half * 512;
    const float* wvp = Wv + (size_t)(half * 512) * D_FEAT + dp;
    double a0 = 0.0, a1 = 0.0, a2 = 0.0, a3 = 0.0;
#pragma unroll 2
    for (int d = 0; d < 512; d += 4) {
        a0 += wc[d + 0] * (double)wvp[(size_t)(d + 0) * D_FEAT];
        a1 += wc[d + 1] * (double)wvp[(size_t)(d + 1) * D_FEAT];
        a2 += wc[d + 2] * (double)wvp[(size_t)(d + 2) * D_FEAT];
        a3 += wc[d + 3] * (double)wvp[(size_t)(d + 3) * D_FEAT];
    }
    partl[half][dpl] = (a0 + a1) + (a2 + a3);
    __syncthreads();
    if (half == 0) {
        double acc = (double)bv[dp] + partl[0][dpl] + partl[1][dpl];
        out[(size_t)(C_CLUST * K_TOP * D_FEAT) + c * D_FEAT + dp] = (float)acc;
    }
}

extern "C" void kernel_launch(void* const* d_in, const int* in_sizes, int n_in,
                              void* d_out, int out_size, void* d_ws, size_t ws_size,
                              hipStream_t stream) {
    const float* feats     = (const float*)d_in[0];  // [8,16384,1024]
    const float* key_feats = (const float*)d_in[1];  // [8,1,1024]
    const float* Wq        = (const float*)d_in[2];  // [1024,128]
    const float* bq        = (const float*)d_in[3];  // [128]
    const float* Wv        = (const float*)d_in[4];  // [1024,1024]
    const float* bv        = (const float*)d_in[5];  // [1024]
    float* out = (float*)d_out;

    char* ws = (char*)d_ws;
    float*  scores  = (float*)(ws + 0);                            // 524288
    double* qk_part = (double*)(ws + 524288);                      // 131072
    double* r       = (double*)(ws + 655360);                      // 65536
    double* b0      = (double*)(ws + 720896);                      // 64
    unsigned long long* cand = (unsigned long long*)(ws + 720960); // 8*32*128*8 = 262144
    double*   Ssum  = (double*)(ws + 983104);                      // 2048
    unsigned* mxkey = (unsigned*)(ws + 985152);                    // 1024
    double*   w_part = (double*)(ws + 986176);                     // 262144 (end 1248320)

    hipLaunchKernelGGL(qk_kernel,           dim3(C_CLUST * 16), dim3(128), 0, stream,
                       key_feats, Wq, qk_part);
    hipLaunchKernelGGL(r_kernel,            dim3(2048), dim3(256), 0, stream,
                       Wq, bq, qk_part, r, b0);
    hipLaunchKernelGGL(score_kernel,        dim3(2048), dim3(256), 0, stream,
                       feats, r, b0, scores);
    hipLaunchKernelGGL(chunksort_kernel,    dim3(256),  dim3(256), 0, stream,
                       scores, cand, mxkey, Ssum);
    hipLaunchKernelGGL(gather_merge_kernel, dim3(128),  dim3(256), 0, stream,
                       feats, cand, mxkey, Ssum, out, w_part);
    hipLaunchKernelGGL(fusion_kernel,       dim3(64),   dim3(256), 0, stream,
                       w_part, Wv, bv, out);
}